// Round 10
// baseline (132.710 us; speedup 1.0000x reference)
//
#include <hip/hip_runtime.h>
#include <stdint.h>

// Problem constants (fixed by setup_inputs): B=32, N=512, D=512
#define BATCH 32
#define NDIM 512
#define DDIM 512
#define WELEMS (DDIM * DDIM)           // 262144

typedef _Float16 f16x8 __attribute__((ext_vector_type(8)));
typedef float f32x4 __attribute__((ext_vector_type(4)));

__device__ __forceinline__ f16x8 cvt8(float4 u0, float4 u1) {
    f16x8 r;
    r[0] = (_Float16)u0.x; r[1] = (_Float16)u0.y;
    r[2] = (_Float16)u0.z; r[3] = (_Float16)u0.w;
    r[4] = (_Float16)u1.x; r[5] = (_Float16)u1.y;
    r[6] = (_Float16)u1.z; r[7] = (_Float16)u1.w;
    return r;
}

// ---------------- pass 0: W fp32 -> fp16 transpose only ----------------------------
// [R8: prep's X-convert pass deleted — fused now reads X fp32 directly. Only the
//  0.5 MB Wt transpose remains (fragments need e-major rows; W native is d-major).]
__global__ __launch_bounds__(256) void prep_wt(const float* __restrict__ W,
                                               _Float16* __restrict__ Wt) {
    __shared__ float tile[32][33];
    int t = blockIdx.x;               // 0..255
    int bx = t & 15;                  // e-tile
    int by = t >> 4;                  // d-tile
    int tx = threadIdx.x & 31;
    int ty = threadIdx.x >> 5;        // 0..7
    for (int r = ty; r < 32; r += 8)
        tile[r][tx] = W[(by * 32 + r) * DDIM + bx * 32 + tx];
    __syncthreads();
    for (int r = ty; r < 32; r += 8)
        Wt[(size_t)(bx * 32 + r) * DDIM + by * 32 + tx] = (_Float16)tile[tx][r];
}

// ---------------- fused: S_b = (X_b @ W) @ X_b^T + bias, diag = 0 -------------------
// [R8/R9 redesign — DELETE ALL B-STAGING (R9 = resubmit after infra failure; kernel
//  has never executed). Post-mortem of R5 (ran R8 round: passed, fused < 42.3 µs,
//  censored by 42 µs poison fills): each wave's B-strip had ZERO intra-block reuse
//  (wave wv is the only consumer of e-rows/X-rows wv*64..+63) -> LDS staging of B
//  was pure overhead (Common-mistake #7) AND made the kernel LDS-pipe-bound:
//  8 waves x 8 ds_read_b128 x ~12cy ≈ 768 cy/CU/K-iter vs ~155 cy of MFMA.
//  Fix: B-fragments are 8 k-contiguous elements/lane -> load straight from global
//  to registers (phase 1: 16 B fp16 from Wt; phase 2: 2x16 B fp32 from X + cvt).
//  L2 serves them (Wt 0.5 MB resident everywhere; X_b 1 MB pinned per-XCD by
//  blk%8=batch%8). Compiler scoreboard on register loads = counted-vmcnt pipelining
//  for free (1-tile manual prefetch, consumed next iter). No inline asm, no vmcnt
//  ledger, ZERO in-loop barriers — AY is read-only within each phase; 3 __syncthreads
//  total. LDS = AY 64 KB only (A-chunks, reused 8x by all waves; then Ylds).
//  Also deletes the Xh intermediate: X fp32 read once (33.5 MB), no 16.8 MB write +
//  re-read, and prep's X pass (~8 µs) is gone.
//  R9 audit: fragment equivalence to R5 proven (involution cancels: (quad^s)^s=quad,
//  so register-direct loads fetch element-for-element what Bs reads resolved to);
//  values bit-identical to the R1 harness-passed kernel. All fragment loads 16B-
//  aligned. Phase-2 live set ~180 VGPR < 256 cap; compile-time indexing only.]
//
// Grid: 256 blocks = rslice*32 + batch (blk%8 = batch%8 -> one batch's 8 row-slice
// blocks share an XCD). 512 threads, 1 block/CU (VGPR ~180 for the fp32 prefetch).
__global__ __launch_bounds__(512, 2) void fused(const float* __restrict__ X,
                                                const _Float16* __restrict__ Wt,
                                                float* __restrict__ Sout,
                                                const float* __restrict__ bias_ptr) {
    // AY: phase 1 = A-chunks [16 kt][4 rc][16 row][32 col] fp16; then Ylds[64][512].
    __shared__ __align__(16) _Float16 AY[64 * 512];        // 64 KB (only LDS)

    const int tid  = threadIdx.x;
    const int lane = tid & 63;
    const int wv   = tid >> 6;        // 0..7
    const int quad = lane >> 4;       // 0..3
    const int l16  = lane & 15;

    const int lr2 = lane >> 2;                    // row within 16x32 chunk (0..15)
    const int lc2 = lane & 3;                     // physical 16B slot (0..3)
    const int lk2 = (lc2 ^ ((lr2 >> 1) & 3)) * 8; // swizzled logical col (rule 21)
    const int paK = (quad ^ ((l16 >> 1) & 3)) * 8; // fragment read slot (same invol.)

    const int blk   = blockIdx.x;     // 256 blocks
    const int batch = blk & 31;
    const int r0    = (blk >> 5) * 64;

    const float* Xb = X + (size_t)batch * (NDIM * DDIM);   // fp32 batch base

    // per-wave global fragment row bases (B operands, register-direct)
    const _Float16* gb1[4];           // phase 1: Wt rows e = wv*64+nt*16+l16
    const float*    gb2[4];           // phase 2: X_b rows j = wv*64+nt*16+l16 (fp32)
#pragma unroll
    for (int nt = 0; nt < 4; ++nt) {
        const int row = wv * 64 + nt * 16 + l16;
        gb1[nt] = Wt + (size_t)row * DDIM + quad * 8;
        gb2[nt] = Xb + (size_t)row * DDIM + quad * 8;
    }

    f32x4 acc[4][4];
#pragma unroll
    for (int i = 0; i < 4; ++i)
#pragma unroll
        for (int j = 0; j < 4; ++j)
            acc[i][j] = (f32x4){0.f, 0.f, 0.f, 0.f};

    // ---- prologue: preload phase-1 B tile 0 (regs), then reg-stage A = X rows
    // r0..r0+64 fp32 -> cvt -> AY (same byte placement gl_lds16 produced in R5:
    // linear dest chunkbase + lr2*32 + lc2*8, pre-swizzled global col lk2).
    f16x8 bb[4];
#pragma unroll
    for (int nt = 0; nt < 4; ++nt)
        bb[nt] = *(const f16x8*)(gb1[nt]);
#pragma unroll
    for (int c = 0; c < 8; ++c) {
        const int kt = wv * 2 + (c >> 2);         // k-tile 0..15 (2 per wave)
        const int rc = c & 3;                     // row-chunk 0..3
        const float* g = Xb + (size_t)(r0 + rc * 16 + lr2) * DDIM + kt * 32 + lk2;
        float4 u0 = *(const float4*)g;
        float4 u1 = *(const float4*)(g + 4);
        *(f16x8*)&AY[(kt * 4 + rc) * 512 + lr2 * 32 + lc2 * 8] = cvt8(u0, u1);
    }
    __syncthreads();                  // A visible; (drains prologue, once — cheap)

    // ================= phase 1: Y = X_b[r0:r0+64][:] @ Wt^T  (16 iters, BK=32) =====
    // No barriers, no LDS for B: bb holds tile it (loaded prev iter), bn prefetches.
#pragma unroll
    for (int it = 0; it < 16; ++it) {
        f16x8 bn[4];
        if (it < 15) {
#pragma unroll
            for (int nt = 0; nt < 4; ++nt)
                bn[nt] = *(const f16x8*)(gb1[nt] + (it + 1) * 32);
        }
        f16x8 a[4];
#pragma unroll
        for (int mt = 0; mt < 4; ++mt)
            a[mt] = *(const f16x8*)&AY[(it * 4 + mt) * 512 + l16 * 32 + paK];
#pragma unroll
        for (int mt = 0; mt < 4; ++mt)
#pragma unroll
            for (int nt = 0; nt < 4; ++nt)
                acc[mt][nt] = __builtin_amdgcn_mfma_f32_16x16x32_f16(
                    a[mt], bb[nt], acc[mt][nt], 0, 0, 0);
        if (it < 15) {
#pragma unroll
            for (int nt = 0; nt < 4; ++nt)
                bb[nt] = bn[nt];
        }
    }

    // ---- interphase: Y -> AY as Ylds (e-chunk XOR-swizzled; C/D col=l16,
    // row=quad*4+r, m89-verified). Barrier before overwrite, barrier after publish.
    __syncthreads();                  // all waves' phase-1 AY reads complete
#pragma unroll
    for (int mt = 0; mt < 4; ++mt)
#pragma unroll
        for (int nt = 0; nt < 4; ++nt)
#pragma unroll
            for (int r = 0; r < 4; ++r) {
                int i = mt * 16 + quad * 4 + r;        // Y row (0..63)
                int e = wv * 64 + nt * 16 + l16;       // Y col (0..511)
                int c = e >> 3, j = e & 7;
                AY[i * 512 + (((c ^ (i & 7)) << 3) | j)] = (_Float16)acc[mt][nt][r];
            }
    __syncthreads();                  // Ylds visible (incl. lgkm drain)

    // ================= phase 2: S = Y @ X_b^T  (16 iters, BK=32, barrier-free) =====
#pragma unroll
    for (int i = 0; i < 4; ++i)
#pragma unroll
        for (int j = 0; j < 4; ++j)
            acc[i][j] = (f32x4){0.f, 0.f, 0.f, 0.f};

    float4 c0[4], c1[4];              // fp32 B tile in flight (converted at use)
#pragma unroll
    for (int nt = 0; nt < 4; ++nt) {
        c0[nt] = *(const float4*)(gb2[nt]);
        c1[nt] = *(const float4*)(gb2[nt] + 4);
    }
#pragma unroll
    for (int it = 0; it < 16; ++it) {
        float4 n0[4], n1[4];
        if (it < 15) {
#pragma unroll
            for (int nt = 0; nt < 4; ++nt) {
                n0[nt] = *(const float4*)(gb2[nt] + (it + 1) * 32);
                n1[nt] = *(const float4*)(gb2[nt] + (it + 1) * 32 + 4);
            }
        }
        f16x8 b[4];
#pragma unroll
        for (int nt = 0; nt < 4; ++nt)
            b[nt] = cvt8(c0[nt], c1[nt]);
        const int pay = (((it * 4 + quad) ^ (l16 & 7)) * 8);  // Ylds swizzled col
        f16x8 a[4];
#pragma unroll
        for (int mt = 0; mt < 4; ++mt)
            a[mt] = *(const f16x8*)&AY[(mt * 16 + l16) * 512 + pay];
#pragma unroll
        for (int mt = 0; mt < 4; ++mt)
#pragma unroll
            for (int nt = 0; nt < 4; ++nt)
                acc[mt][nt] = __builtin_amdgcn_mfma_f32_16x16x32_f16(
                    a[mt], b[nt], acc[mt][nt], 0, 0, 0);
        if (it < 15) {
#pragma unroll
            for (int nt = 0; nt < 4; ++nt) {
                c0[nt] = n0[nt];
                c1[nt] = n1[nt];
            }
        }
    }

    // ---- epilogue: bias, zero diagonal, fp32 store
    const float bias = bias_ptr[0];
#pragma unroll
    for (int mt = 0; mt < 4; ++mt)
#pragma unroll
        for (int nt = 0; nt < 4; ++nt)
#pragma unroll
            for (int r = 0; r < 4; ++r) {
                int gi = r0 + mt * 16 + quad * 4 + r;   // row within batch (0..511)
                int gj = wv * 64 + nt * 16 + l16;       // col within batch (0..511)
                float v = acc[mt][nt][r] + bias;
                if (gi == gj) v = 0.f;
                Sout[((size_t)batch * NDIM + gi) * NDIM + gj] = v;
            }
}

extern "C" void kernel_launch(void* const* d_in, const int* in_sizes, int n_in,
                              void* d_out, int out_size, void* d_ws, size_t ws_size,
                              hipStream_t stream) {
    const float* X  = (const float*)d_in[0];   // (32, 512, 512) fp32
    const float* W  = (const float*)d_in[1];   // (512, 512) fp32
    const float* bp = (const float*)d_in[2];   // scalar fp32
    float* out = (float*)d_out;                // (32, 512, 512) fp32

    // workspace: only Wt (fp16, 512 KB)
    _Float16* Wt = (_Float16*)d_ws;

    // pass 0: W transpose only (X is consumed fp32 directly by fused)
    prep_wt<<<256, 256, 0, stream>>>(W, Wt);

    // fused: per (batch, 64-row slice): A reg-staged once into LDS; B operands
    // register-direct from global (Wt fp16 / X fp32+cvt); Ylds reuses A's LDS.
    fused<<<256, 512, 0, stream>>>(X, Wt, out, bp);

    (void)in_sizes; (void)n_in; (void)out_size; (void)ws_size;
}

// Round 15
// 105.638 us; speedup vs baseline: 1.2563x; 1.2563x over previous
//
#include <hip/hip_runtime.h>
#include <stdint.h>

// Problem constants (fixed by setup_inputs): B=32, N=512, D=512
#define BATCH 32
#define NDIM 512
#define DDIM 512
#define XELEMS (BATCH * NDIM * DDIM)   // 8388608

typedef _Float16 f16x8 __attribute__((ext_vector_type(8)));
typedef float f32x4 __attribute__((ext_vector_type(4)));

__device__ __forceinline__ f16x8 cvt8(float4 u0, float4 u1) {
    f16x8 r;
    r[0] = (_Float16)u0.x; r[1] = (_Float16)u0.y;
    r[2] = (_Float16)u0.z; r[3] = (_Float16)u0.w;
    r[4] = (_Float16)u1.x; r[5] = (_Float16)u1.y;
    r[6] = (_Float16)u1.z; r[7] = (_Float16)u1.w;
    return r;
}

// --- async global -> LDS, 16 bytes per lane (global_load_lds_dwordx4) ---
__device__ __forceinline__ void gl_lds16(const _Float16* g, _Float16* l) {
    __builtin_amdgcn_global_load_lds(
        (const __attribute__((address_space(1))) unsigned int*)(g),
        (__attribute__((address_space(3))) unsigned int*)(l),
        16, 0, 0);
}

// counted vmcnt wait + scheduling fence (rule 18)
#define WAITVM(N) do { asm volatile("s_waitcnt vmcnt(" #N ")" ::: "memory"); \
                       __builtin_amdgcn_sched_barrier(0); } while (0)

// ===================================================================================
// [R14 — TILED-SWIZZLED GLOBAL LAYOUTS. Withdraws the R10 depth-prefetch A/B with
//  cause: R8's 4500 cy/iter exceeds any latency mechanism (serial load→use ≤1100cy)
//  -> depth can't fix it. New model: fused family is L2->CU TRANSACTION-throughput
//  bound, time ∝ per-block staged bytes: R5 1.06MB -> ~41µs, R8 1.6MB -> 60.5µs
//  (predicted ratio 1.53, measured 1.48); R1 vs R5 = barrier tax only. All staging
//  loads were 16-line STRIDED (rule-21 pre-swizzle traded global contiguity for LDS
//  layout). Fix: bake the swizzle into prep's WRITES — store Xh,Wt K-tile-major:
//    Xh_t[b][kt][ch][r][s][j] (fp16) = X[b][ch*16+r][kt*32 + (s^((r>>1)&3))*8 + j]
//    Wt_t[kt][ch][r][s][j]    (fp16) = W[kt*32 + (s^((r>>1)&3))*8 + j][ch*16+r]
//  Each (kt,ch) chunk = 1KB contiguous; fused's gl_lds reads lane-sequential 1KB
//  bursts yet lands the BYTE-IDENTICAL LDS image the HW-passed R5 kernel consumes.
//  fused below = R5 verbatim (ledger audited R6/R7; passed on HW in the R8 round,
//  110.0µs total banked) with only the staging SOURCE addresses changed to linear.]
// ===================================================================================

// ---------------- pass 0: build Xh_t (fp32->fp16, tiled+swizzled) and Wt_t ---------
__global__ __launch_bounds__(256) void prep(const float* __restrict__ X,
                                            _Float16* __restrict__ XhT,
                                            const float* __restrict__ W,
                                            _Float16* __restrict__ WtT) {
    int bid = blockIdx.x;
    if (bid < 4096) {
        // X part: 16384 groups (b,kt,ch), 4 per block; wave-contiguous 1KB writes.
        int g    = bid * 4 + (threadIdx.x >> 6);
        int lane = threadIdx.x & 63;
        int b  = g >> 9;             // 0..31
        int kt = (g >> 5) & 15;      // 0..15
        int ch = g & 31;             // 0..31
        int r = lane >> 2, s = lane & 3;
        int col = kt * 32 + ((s ^ ((r >> 1) & 3)) << 3);   // pre-swizzled source col
        const float* src = X + ((size_t)(b * 512 + ch * 16 + r)) * DDIM + col;
        float4 u0 = *(const float4*)src;
        float4 u1 = *(const float4*)(src + 4);
        *(f16x8*)&XhT[(size_t)g * 512 + lane * 8] = cvt8(u0, u1);
    } else {
        // W part: 256 tiles of 32x32; LDS transpose then tiled-swizzled 16B writes.
        __shared__ float tile[32][33];
        int t  = bid - 4096;
        int bx = t & 15;             // e-tile
        int by = t >> 4;             // d-tile == kt
        int tx = threadIdx.x & 31;
        int ty = threadIdx.x >> 5;   // 0..7
        for (int rr = ty; rr < 32; rr += 8)
            tile[rr][tx] = W[(by * 32 + rr) * DDIM + bx * 32 + tx]; // [d-within][e-within]
        __syncthreads();
        int idx = threadIdx.x;       // threads 0..127 write one 16B slot each
        if (idx < 128) {
            int er = idx >> 2;                  // e-within 0..31
            int sp = idx & 3;                   // physical slot
            int rr = er & 15;                   // r within chunk
            int sl = sp ^ ((rr >> 1) & 3);      // logical slot
            f16x8 v;
#pragma unroll
            for (int j = 0; j < 8; ++j)
                v[j] = (_Float16)tile[sl * 8 + j][er];
            int ch = bx * 2 + (er >> 4);
            *(f16x8*)&WtT[((size_t)(by * 32 + ch)) * 512 + rr * 32 + sp * 8] = v;
        }
    }
}

// ---------------- fused: S_b = (X_b @ W) @ X_b^T + bias, diag = 0 -------------------
// Structure = R5 (3 barriers, per-wave counted vmcnt(4), B strips wave-private,
// A staged once, Ylds reuses A's LDS). Grid: 256 blocks = rslice*32 + batch
// (blk%8 = batch%8 -> one batch's 8 row-slice blocks share an XCD).
__global__ __launch_bounds__(512) void fused(const _Float16* __restrict__ XhT,
                                             const _Float16* __restrict__ WtT,
                                             float* __restrict__ Sout,
                                             const float* __restrict__ bias_ptr) {
    // AY: phase 1 = A-chunks [16 kt][4 rc][16 r][32 col] fp16; then Ylds[64][512].
    __shared__ __align__(16) _Float16 AY[64 * 512];        // 64 KB
    __shared__ __align__(16) _Float16 Bs[2][8 * 2048];     // 64 KB: dbuf x 8 strips

    const int tid  = threadIdx.x;
    const int lane = tid & 63;
    const int wv   = tid >> 6;        // 0..7
    const int quad = lane >> 4;       // 0..3
    const int l16  = lane & 15;
    const int l8   = lane * 8;        // fp16 offset of this lane's 16B in a chunk

    // fragment read slot (read side of the baked involution; rows ≡ l16 mod 16)
    const int paK = (quad ^ ((l16 >> 1) & 3)) * 8;

    const int blk   = blockIdx.x;     // 256 blocks
    const int batch = blk & 31;
    const int r0    = (blk >> 5) * 64;
    const int ch0   = r0 >> 4;        // first A row-chunk (0..31, step 4)

    const _Float16* Xt = XhT + (size_t)(batch * 16) * 32 * 512;  // batch's 16 kt-tiles

    f32x4 acc[4][4];
#pragma unroll
    for (int i = 0; i < 4; ++i)
#pragma unroll
        for (int j = 0; j < 4; ++j)
            acc[i][j] = (f32x4){0.f, 0.f, 0.f, 0.f};

    // ---- prologue: stage ALL of A (64 chunks, 8 per wave; 1KB sequential each),
    //      then B tile 0 (wave-own strip, 4 chunks). A oldest -> vmcnt(4) waits A.
#pragma unroll
    for (int c = 0; c < 8; ++c) {
        const int kt = wv * 2 + (c >> 2);         // k-tile (2 per wave)
        const int rc = c & 3;                     // row-chunk 0..3
        gl_lds16(Xt + ((size_t)(kt * 32 + ch0 + rc)) * 512 + l8,
                 &AY[(kt * 4 + rc) * 512]);
    }
#pragma unroll
    for (int t = 0; t < 4; ++t)
        gl_lds16(WtT + ((size_t)(0 * 32 + wv * 4 + t)) * 512 + l8,
                 &Bs[0][wv * 2048 + t * 512]);
    WAITVM(4);                         // A's 8 loads (oldest) complete; B0 in flight
    __builtin_amdgcn_s_barrier();      // A visible to all waves

    // ================= phase 1: Y = X_b[r0:r0+64][:] @ Wt^T  (16 iters, BK=32) =====
#pragma unroll
    for (int it = 0; it < 15; ++it) {
        const int buf = it & 1;
        const int ktn = it + 1;
#pragma unroll
        for (int t = 0; t < 4; ++t)    // stage next tile into buf^1 (wave-own strip)
            gl_lds16(WtT + ((size_t)(ktn * 32 + wv * 4 + t)) * 512 + l8,
                     &Bs[buf ^ 1][wv * 2048 + t * 512]);
        WAITVM(4);                     // tile it (oldest 4) landed; it+1 in flight
        f16x8 a[4], b[4];
#pragma unroll
        for (int mt = 0; mt < 4; ++mt)
            a[mt] = *(const f16x8*)&AY[(it * 4 + mt) * 512 + l16 * 32 + paK];
#pragma unroll
        for (int nt = 0; nt < 4; ++nt)
            b[nt] = *(const f16x8*)&Bs[buf][wv * 2048 + nt * 512 + l16 * 32 + paK];
#pragma unroll
        for (int mt = 0; mt < 4; ++mt)
#pragma unroll
            for (int nt = 0; nt < 4; ++nt)
                acc[mt][nt] = __builtin_amdgcn_mfma_f32_16x16x32_f16(
                    a[mt], b[nt], acc[mt][nt], 0, 0, 0);
    }
    {   // ---- peeled it = 15: prefetch PHASE-2 tile 0 (Xh_t, et=0) instead
        const int buf = 15 & 1;        // = 1; prefetch -> Bs[0] = phase-2 tile 0
#pragma unroll
        for (int t = 0; t < 4; ++t)
            gl_lds16(Xt + ((size_t)(0 * 32 + wv * 4 + t)) * 512 + l8,
                     &Bs[buf ^ 1][wv * 2048 + t * 512]);
        WAITVM(4);
        f16x8 a[4], b[4];
#pragma unroll
        for (int mt = 0; mt < 4; ++mt)
            a[mt] = *(const f16x8*)&AY[(15 * 4 + mt) * 512 + l16 * 32 + paK];
#pragma unroll
        for (int nt = 0; nt < 4; ++nt)
            b[nt] = *(const f16x8*)&Bs[buf][wv * 2048 + nt * 512 + l16 * 32 + paK];
#pragma unroll
        for (int mt = 0; mt < 4; ++mt)
#pragma unroll
            for (int nt = 0; nt < 4; ++nt)
                acc[mt][nt] = __builtin_amdgcn_mfma_f32_16x16x32_f16(
                    a[mt], b[nt], acc[mt][nt], 0, 0, 0);
    }

    // ---- interphase (barriers #2, #3 — R5 verbatim; prefetch stays in flight).
    __builtin_amdgcn_s_barrier();
#pragma unroll
    for (int mt = 0; mt < 4; ++mt)
#pragma unroll
        for (int nt = 0; nt < 4; ++nt)
#pragma unroll
            for (int r = 0; r < 4; ++r) {
                int i = mt * 16 + quad * 4 + r;        // Y row (0..63)
                int e = wv * 64 + nt * 16 + l16;       // Y col (0..511)
                int c = e >> 3, j = e & 7;
                AY[i * 512 + (((c ^ (i & 7)) << 3) | j)] = (_Float16)acc[mt][nt][r];
            }
    asm volatile("s_waitcnt lgkmcnt(0)" ::: "memory");
    __builtin_amdgcn_s_barrier();      // Ylds visible

    // ================= phase 2: S = Y @ X_b^T  (16 iters, BK=32, barrier-free) =====
#pragma unroll
    for (int i = 0; i < 4; ++i)
#pragma unroll
        for (int j = 0; j < 4; ++j)
            acc[i][j] = (f32x4){0.f, 0.f, 0.f, 0.f};

#pragma unroll
    for (int it = 0; it < 15; ++it) {
        const int buf = it & 1;
        const int etn = it + 1;
#pragma unroll
        for (int t = 0; t < 4; ++t)    // stage next e-tile (wave-own X strip)
            gl_lds16(Xt + ((size_t)(etn * 32 + wv * 4 + t)) * 512 + l8,
                     &Bs[buf ^ 1][wv * 2048 + t * 512]);
        WAITVM(4);
        const int pay = (((it * 4 + quad) ^ (l16 & 7)) * 8);  // Ylds swizzled col
        f16x8 a[4], b[4];
#pragma unroll
        for (int mt = 0; mt < 4; ++mt)
            a[mt] = *(const f16x8*)&AY[(mt * 16 + l16) * 512 + pay];
#pragma unroll
        for (int nt = 0; nt < 4; ++nt)
            b[nt] = *(const f16x8*)&Bs[buf][wv * 2048 + nt * 512 + l16 * 32 + paK];
#pragma unroll
        for (int mt = 0; mt < 4; ++mt)
#pragma unroll
            for (int nt = 0; nt < 4; ++nt)
                acc[mt][nt] = __builtin_amdgcn_mfma_f32_16x16x32_f16(
                    a[mt], b[nt], acc[mt][nt], 0, 0, 0);
    }
    {   // ---- peeled it = 15: drain the last own-tile
        const int buf = 15 & 1;
        WAITVM(0);
        const int pay = (((15 * 4 + quad) ^ (l16 & 7)) * 8);
        f16x8 a[4], b[4];
#pragma unroll
        for (int mt = 0; mt < 4; ++mt)
            a[mt] = *(const f16x8*)&AY[(mt * 16 + l16) * 512 + pay];
#pragma unroll
        for (int nt = 0; nt < 4; ++nt)
            b[nt] = *(const f16x8*)&Bs[buf][wv * 2048 + nt * 512 + l16 * 32 + paK];
#pragma unroll
        for (int mt = 0; mt < 4; ++mt)
#pragma unroll
            for (int nt = 0; nt < 4; ++nt)
                acc[mt][nt] = __builtin_amdgcn_mfma_f32_16x16x32_f16(
                    a[mt], b[nt], acc[mt][nt], 0, 0, 0);
    }

    // ---- epilogue: bias, zero diagonal, fp32 store
    const float bias = bias_ptr[0];
#pragma unroll
    for (int mt = 0; mt < 4; ++mt)
#pragma unroll
        for (int nt = 0; nt < 4; ++nt)
#pragma unroll
            for (int r = 0; r < 4; ++r) {
                int gi = r0 + mt * 16 + quad * 4 + r;   // row within batch
                int gj = wv * 64 + nt * 16 + l16;       // col within batch
                float v = acc[mt][nt][r] + bias;
                if (gi == gj) v = 0.f;
                Sout[((size_t)batch * NDIM + gi) * NDIM + gj] = v;
            }
}

extern "C" void kernel_launch(void* const* d_in, const int* in_sizes, int n_in,
                              void* d_out, int out_size, void* d_ws, size_t ws_size,
                              hipStream_t stream) {
    const float* X  = (const float*)d_in[0];   // (32, 512, 512) fp32
    const float* W  = (const float*)d_in[1];   // (512, 512) fp32
    const float* bp = (const float*)d_in[2];   // scalar fp32
    float* out = (float*)d_out;                // (32, 512, 512) fp32

    // workspace (fp16): XhT[8388608] | WtT[262144]
    _Float16* XhT = (_Float16*)d_ws;
    _Float16* WtT = XhT + XELEMS;

    // pass 0: tiled+swizzled fp16 layouts (4096 X-blocks + 256 W-blocks)
    prep<<<4096 + 256, 256, 0, stream>>>(X, XhT, W, WtT);

    // fused: R5 structure, staging now reads lane-sequential 1KB chunks
    fused<<<256, 512, 0, stream>>>(XhT, WtT, out, bp);

    (void)in_sizes; (void)n_in; (void)out_size; (void)ws_size;
}